// Round 8
// baseline (402.057 us; speedup 1.0000x reference)
//
#include <hip/hip_runtime.h>

__device__ __forceinline__ float2 cmul(float2 a, float2 b) {
    return make_float2(a.x*b.x - a.y*b.y, a.x*b.y + a.y*b.x);
}
__device__ __forceinline__ float2 cadd(float2 a, float2 b){ return make_float2(a.x+b.x, a.y+b.y); }
__device__ __forceinline__ float2 csub(float2 a, float2 b){ return make_float2(a.x-b.x, a.y-b.y); }

// Wave-local LDS "barrier": all lane-exchange in the FFTs is within ONE wave
// (scratch regions are per-wave disjoint), so no s_barrier is needed.
__device__ __forceinline__ void wsync() {
    asm volatile("s_waitcnt lgkmcnt(0)" ::: "memory");
}

// multiply by (0, SGN): forward SGN=-1, inverse SGN=+1
template<int SGN> __device__ __forceinline__ float2 mul_i(float2 a) {
    return (SGN > 0) ? make_float2(-a.y, a.x) : make_float2(a.y, -a.x);
}
// W8^1 = (r, SGN*r), r = sqrt(0.5)
template<int SGN> __device__ __forceinline__ float2 mul_w81(float2 a) {
    const float r = 0.70710678118654752440f;
    return (SGN > 0) ? make_float2(r*(a.x - a.y), r*(a.x + a.y))
                     : make_float2(r*(a.x + a.y), r*(a.y - a.x));
}
// W8^3 = (-r, SGN*r)
template<int SGN> __device__ __forceinline__ float2 mul_w83(float2 a) {
    const float r = 0.70710678118654752440f;
    return (SGN > 0) ? make_float2(-r*(a.x + a.y), r*(a.x - a.y))
                     : make_float2(r*(a.y - a.x), -r*(a.x + a.y));
}

// 8-point DFT in registers, natural-order output: out[q] = sum_k in[k] W8^{SGN*qk}
template<int SGN>
__device__ __forceinline__ void bfly8(float2 v[8]) {
    float2 s0 = cadd(v[0], v[4]), d0 = csub(v[0], v[4]);
    float2 s1 = cadd(v[1], v[5]), d1 = csub(v[1], v[5]);
    float2 s2 = cadd(v[2], v[6]), d2 = csub(v[2], v[6]);
    float2 s3 = cadd(v[3], v[7]), d3 = csub(v[3], v[7]);
    d1 = mul_w81<SGN>(d1);
    d2 = mul_i<SGN>(d2);
    d3 = mul_w83<SGN>(d3);
    float2 p0 = cadd(s0, s2), q0 = csub(s0, s2);
    float2 p1 = cadd(s1, s3), q1 = mul_i<SGN>(csub(s1, s3));
    float2 P0 = cadd(d0, d2), Q0 = csub(d0, d2);
    float2 P1 = cadd(d1, d3), Q1 = mul_i<SGN>(csub(d1, d3));
    v[0] = cadd(p0, p1);
    v[4] = csub(p0, p1);
    v[2] = cadd(q0, q1);
    v[6] = csub(q0, q1);
    v[1] = cadd(P0, P1);
    v[5] = csub(P0, P1);
    v[3] = cadd(Q0, Q1);
    v[7] = csub(Q0, Q1);
}

// v[q] *= W^{SGN*q}, W = cis(2*pi*frac)
template<int SGN>
__device__ __forceinline__ void twiddle7(float2 v[8], float frac) {
    const float ang = (SGN > 0 ? 6.2831853071795864769f : -6.2831853071795864769f) * frac;
    float sn, cs; __sincosf(ang, &sn, &cs);
    const float2 w1 = make_float2(cs, sn);
    float2 w = w1;
    v[1] = cmul(v[1], w);
#pragma unroll
    for (int q = 2; q < 8; ++q) { w = cmul(w, w1); v[q] = cmul(v[q], w); }
}

// Swizzles for the two LDS exchanges (both uniform 4 accesses/bank for b64):
//   f1(a) = a + 2*(a>>6)  (exchange stride-64 <-> stride-8 pattern)
//   f2(a) = a + (a>>3)    (exchange stride-8  <-> contiguous pattern)

// Forward 512-pt FFT, one wave, lane l (0..63), v preloaded with h = l+64k.
// Output: v[q] = spectrum value at position p = 8l+q (freq = octal-digit-rev(p)).
// S: per-wave scratch, >= 575 float2. Wave-local sync only -- no block barriers.
__device__ __forceinline__ void fft512_fwd(float2 v[8], float2* S, int l) {
    const int g = l >> 3, j = l & 7;
    bfly8<-1>(v);
    twiddle7<-1>(v, (float)l * (1.0f/512.0f));
#pragma unroll
    for (int q = 0; q < 8; ++q) S[66*q + l] = v[q];          // f1(64q+l)
    wsync();
#pragma unroll
    for (int k = 0; k < 8; ++k) v[k] = S[66*g + j + 8*k];    // f1(64g+j+8k)
    bfly8<-1>(v);
    twiddle7<-1>(v, (float)j * (1.0f/64.0f));
#pragma unroll
    for (int q = 0; q < 8; ++q) S[72*g + 9*q + j] = v[q];    // f2(64g+8q+j)
    wsync();
#pragma unroll
    for (int k = 0; k < 8; ++k) v[k] = S[9*l + k];           // f2(8l+k)
    bfly8<-1>(v);
}

// Inverse (unscaled, x512): input v[q] = value at position 8l+q, output
// v[k] = natural-order sample at h = l+64k. Exact mirror of fft512_fwd.
__device__ __forceinline__ void fft512_inv(float2 v[8], float2* S, int l) {
    const int g = l >> 3, j = l & 7;
    bfly8<1>(v);
#pragma unroll
    for (int k = 0; k < 8; ++k) S[9*l + k] = v[k];
    wsync();
#pragma unroll
    for (int q = 0; q < 8; ++q) v[q] = S[72*g + 9*q + j];
    twiddle7<1>(v, (float)j * (1.0f/64.0f));
    bfly8<1>(v);
#pragma unroll
    for (int k = 0; k < 8; ++k) S[66*g + j + 8*k] = v[k];
    wsync();
#pragma unroll
    for (int q = 0; q < 8; ++q) v[q] = S[66*q + l];
    twiddle7<1>(v, (float)l * (1.0f/512.0f));
    bfly8<1>(v);
}

__device__ __forceinline__ int drev(int x) {   // reverse 3 octal digits of 9-bit x
    return ((x & 7) << 6) | (x & 56) | (x >> 6);
}

// Prologue: Hp[pw*512 + ph] = Hh[drev(ph)][drev(pw)], Hh = Hermitian part of
// the filter (for real x, Re(ifft2(fft2(x)*H)) == ifft2(fft2(x)*Hh), a real
// linear map, so two planes pack as re/im of one complex plane).
// Hp now lives in the spare ws region (NOT d_out: with batched pass3, d_out
// planes are written while later batches still need Hp).
__global__ __launch_bounds__(256) void permH(const float* __restrict__ Hr,
                                             const float* __restrict__ Hi,
                                             float2* __restrict__ Hp) {
    const int pw = blockIdx.x;
    const int kw = drev(pw);
    const int nw = (512 - kw) & 511;
    for (int ph = threadIdx.x; ph < 512; ph += 256) {
        const int kh = drev(ph);
        const int nh = (512 - kh) & 511;
        const float hr = 0.5f * (Hr[(kh << 9) + kw] + Hr[(nh << 9) + nw]);
        const float hi = 0.5f * (Hi[(kh << 9) + kw] - Hi[(nh << 9) + nw]);
        Hp[(pw << 9) + ph] = make_float2(hr, hi);
    }
}

// L3-BATCHED PIPELINE (this round's change): the 64 packed planes are
// processed in batches of 16 (32 MB ws slice). pass1(b) writes the slice,
// pass2(b) reads+rewrites it ~20us later, pass3(b) reads it -- at 32 MB the
// slice stays resident in the 256 MiB Infinity Cache across the kernel
// boundaries (evidence: round-7 FETCH showed ~50% cross-kernel L3 retention
// even for 128 MB), so intermediate traffic runs at L3 speed and HBM sees
// only the compulsory x read and out write.

// Pass 1: forward FFT along W. 4 waves/block, one row per wave.
// Rows of batch [img0, img0+16).
__global__ __launch_bounds__(256) void pass1_rows(const float* __restrict__ x,
                                                  float2* __restrict__ ws,
                                                  int img0) {
    __shared__ float2 smem[4 * 577];
    const int t = threadIdx.x;
    const int l = t & 63, w = t >> 6;
    float2* S = smem + w * 577;
    const size_t r   = (size_t)blockIdx.x * 4 + w;   // row-in-batch 0..8191
    const size_t img = (size_t)img0 + (r >> 9);      // packed plane
    const size_t h   = r & 511;
    const float* src1 = x + ((img * 2) << 18) + (h << 9);
    const float* src2 = src1 + (1 << 18);
    float2 v[8];
#pragma unroll
    for (int k = 0; k < 8; ++k) v[k] = make_float2(src1[l + 64*k], src2[l + 64*k]);
    fft512_fwd(v, S, l);
    float4* dst = (float4*)(ws + (img * 512 + h) * 512 + 8*l);  // 64B/lane
#pragma unroll
    for (int q = 0; q < 4; ++q)
        dst[q] = make_float4(v[2*q].x, v[2*q].y, v[2*q+1].x, v[2*q+1].y);
}

// Pass 2: 8 adjacent columns per block (512 thr = 8 waves), one column per
// wave, planes [img0, img0+16). Coop line-complete staging (float4, 16B/lane);
// FFT scratch aliases the staging buffer.
__global__ __launch_bounds__(512) void pass2_cols(float2* __restrict__ ws,
                                                  const float2* __restrict__ Hp,
                                                  int img0) {
    __shared__ float2 smem[4616];      // staging 9*511+7 <= 4606; 8 scratches of 577
    const int t = threadIdx.x;
    const int l = t & 63, w = t >> 6;  // wave id == column-in-tile
    const int img = img0 + (blockIdx.x >> 6);
    const int w0 = (blockIdx.x & 63) * 8;
    float2* base = ws + ((size_t)img << 18) + w0;

    {   // stage-in: float4 per lane (2 adjacent columns), line-complete
        const int c = t & 3, u = t >> 2;       // c: column pair, u: 0..127
#pragma unroll
        for (int k = 0; k < 4; ++k) {
            int h = u + 128*k;
            float4 p = *(const float4*)(base + (size_t)h * 512 + 2*c);
            smem[9*h + 2*c]     = make_float2(p.x, p.y);
            smem[9*h + 2*c + 1] = make_float2(p.z, p.w);
        }
    }
    __syncthreads();
    float2 v[8];
#pragma unroll
    for (int k = 0; k < 8; ++k) v[k] = smem[9*(l + 64*k) + w];
    __syncthreads();                   // staging dead; scratch may alias it
    float2* S = smem + w * 577;
    fft512_fwd(v, S, l);
    {   // filter: kh = drev(8l+q), kw = drev(w0+w) -- pre-baked into Hp
        const float4* hp = (const float4*)(Hp + (((size_t)(w0 + w)) << 9) + 8*l);
#pragma unroll
        for (int q = 0; q < 4; ++q) {
            float4 h2 = hp[q];
            v[2*q]   = cmul(v[2*q],   make_float2(h2.x, h2.y));
            v[2*q+1] = cmul(v[2*q+1], make_float2(h2.z, h2.w));
        }
    }
    fft512_inv(v, S, l);
    __syncthreads();                   // all waves done with scratch
#pragma unroll
    for (int k = 0; k < 8; ++k) smem[9*(l + 64*k) + w] = v[k];
    __syncthreads();
    {   // stage-out, float4 per lane, line-complete
        const int c = t & 3, u = t >> 2;
#pragma unroll
        for (int k = 0; k < 4; ++k) {
            int h = u + 128*k;
            float2 a = smem[9*h + 2*c], b = smem[9*h + 2*c + 1];
            *(float4*)(base + (size_t)h * 512 + 2*c) = make_float4(a.x, a.y, b.x, b.y);
        }
    }
}

// Pass 3: inverse FFT along W, scale 1/512^2; unpack Re -> plane 2m,
// Im -> plane 2m+1. Rows of batch [img0, img0+16).
__global__ __launch_bounds__(256) void pass3_rows(const float2* __restrict__ ws,
                                                  float* __restrict__ out,
                                                  int img0) {
    __shared__ float2 smem[4 * 577];
    const int t = threadIdx.x;
    const int l = t & 63, w = t >> 6;
    float2* S = smem + w * 577;
    const size_t r   = (size_t)blockIdx.x * 4 + w;   // row-in-batch 0..8191
    const size_t img = (size_t)img0 + (r >> 9);
    const size_t h   = r & 511;
    const float4* src = (const float4*)(ws + (img * 512 + h) * 512 + 8*l);
    float2 v[8];
#pragma unroll
    for (int q = 0; q < 4; ++q) {
        float4 p = src[q];
        v[2*q]   = make_float2(p.x, p.y);
        v[2*q+1] = make_float2(p.z, p.w);
    }
    fft512_inv(v, S, l);
    const float sc = 1.0f / (512.0f * 512.0f);
    float* dst1 = out + ((img * 2) << 18) + (h << 9);
    float* dst2 = dst1 + (1 << 18);
#pragma unroll
    for (int k = 0; k < 8; ++k) {
        dst1[l + 64*k] = v[k].x * sc;
        dst2[l + 64*k] = v[k].y * sc;
    }
}

extern "C" void kernel_launch(void* const* d_in, const int* in_sizes, int n_in,
                              void* d_out, int out_size, void* d_ws, size_t ws_size,
                              hipStream_t stream) {
    const float* x  = (const float*)d_in[0];   // [8,16,512,512]
    const float* Hr = (const float*)d_in[1];   // [512,512]
    const float* Hi = (const float*)d_in[2];   // [512,512]
    float* out = (float*)d_out;
    float2* ws = (float2*)d_ws;                // 128 MiB packed-plane workspace
    float2* Hp = ws + ((size_t)64 << 18);      // +2 MiB filter, after the 64 planes

    permH<<<512, 256, 0, stream>>>(Hr, Hi, Hp);
    for (int b = 0; b < 4; ++b) {              // 16 planes (32 MB slice) per batch
        const int img0 = b * 16;
        pass1_rows<<<2048, 256, 0, stream>>>(x, ws, img0);
        pass2_cols<<<1024, 512, 0, stream>>>(ws, Hp, img0);
        pass3_rows<<<2048, 256, 0, stream>>>(ws, out, img0);
    }
}

// Round 9
// 331.117 us; speedup vs baseline: 1.2142x; 1.2142x over previous
//
#include <hip/hip_runtime.h>
#include <hip/hip_fp16.h>

__device__ __forceinline__ float2 cmul(float2 a, float2 b) {
    return make_float2(a.x*b.x - a.y*b.y, a.x*b.y + a.y*b.x);
}
__device__ __forceinline__ float2 cadd(float2 a, float2 b){ return make_float2(a.x+b.x, a.y+b.y); }
__device__ __forceinline__ float2 csub(float2 a, float2 b){ return make_float2(a.x-b.x, a.y-b.y); }

// Wave-local LDS "barrier": all lane-exchange in the FFTs is within ONE wave
// (scratch regions are per-wave disjoint), so no s_barrier is needed.
__device__ __forceinline__ void wsync() {
    asm volatile("s_waitcnt lgkmcnt(0)" ::: "memory");
}

// multiply by (0, SGN): forward SGN=-1, inverse SGN=+1
template<int SGN> __device__ __forceinline__ float2 mul_i(float2 a) {
    return (SGN > 0) ? make_float2(-a.y, a.x) : make_float2(a.y, -a.x);
}
// W8^1 = (r, SGN*r), r = sqrt(0.5)
template<int SGN> __device__ __forceinline__ float2 mul_w81(float2 a) {
    const float r = 0.70710678118654752440f;
    return (SGN > 0) ? make_float2(r*(a.x - a.y), r*(a.x + a.y))
                     : make_float2(r*(a.x + a.y), r*(a.y - a.x));
}
// W8^3 = (-r, SGN*r)
template<int SGN> __device__ __forceinline__ float2 mul_w83(float2 a) {
    const float r = 0.70710678118654752440f;
    return (SGN > 0) ? make_float2(-r*(a.x + a.y), r*(a.x - a.y))
                     : make_float2(r*(a.y - a.x), -r*(a.x + a.y));
}

// 8-point DFT in registers, natural-order output: out[q] = sum_k in[k] W8^{SGN*qk}
template<int SGN>
__device__ __forceinline__ void bfly8(float2 v[8]) {
    float2 s0 = cadd(v[0], v[4]), d0 = csub(v[0], v[4]);
    float2 s1 = cadd(v[1], v[5]), d1 = csub(v[1], v[5]);
    float2 s2 = cadd(v[2], v[6]), d2 = csub(v[2], v[6]);
    float2 s3 = cadd(v[3], v[7]), d3 = csub(v[3], v[7]);
    d1 = mul_w81<SGN>(d1);
    d2 = mul_i<SGN>(d2);
    d3 = mul_w83<SGN>(d3);
    float2 p0 = cadd(s0, s2), q0 = csub(s0, s2);
    float2 p1 = cadd(s1, s3), q1 = mul_i<SGN>(csub(s1, s3));
    float2 P0 = cadd(d0, d2), Q0 = csub(d0, d2);
    float2 P1 = cadd(d1, d3), Q1 = mul_i<SGN>(csub(d1, d3));
    v[0] = cadd(p0, p1);
    v[4] = csub(p0, p1);
    v[2] = cadd(q0, q1);
    v[6] = csub(q0, q1);
    v[1] = cadd(P0, P1);
    v[5] = csub(P0, P1);
    v[3] = cadd(Q0, Q1);
    v[7] = csub(Q0, Q1);
}

// v[q] *= W^{SGN*q}, W = cis(2*pi*frac)
template<int SGN>
__device__ __forceinline__ void twiddle7(float2 v[8], float frac) {
    const float ang = (SGN > 0 ? 6.2831853071795864769f : -6.2831853071795864769f) * frac;
    float sn, cs; __sincosf(ang, &sn, &cs);
    const float2 w1 = make_float2(cs, sn);
    float2 w = w1;
    v[1] = cmul(v[1], w);
#pragma unroll
    for (int q = 2; q < 8; ++q) { w = cmul(w, w1); v[q] = cmul(v[q], w); }
}

// Forward 512-pt FFT, one wave, lane l (0..63), v preloaded with h = l+64k.
// Output: v[q] = spectrum value at position p = 8l+q (freq = octal-digit-rev(p)).
// S: per-wave scratch, >= 575 float2. Wave-local sync only -- no block barriers.
__device__ __forceinline__ void fft512_fwd(float2 v[8], float2* S, int l) {
    const int g = l >> 3, j = l & 7;
    bfly8<-1>(v);
    twiddle7<-1>(v, (float)l * (1.0f/512.0f));
#pragma unroll
    for (int q = 0; q < 8; ++q) S[66*q + l] = v[q];          // f1(64q+l)
    wsync();
#pragma unroll
    for (int k = 0; k < 8; ++k) v[k] = S[66*g + j + 8*k];    // f1(64g+j+8k)
    bfly8<-1>(v);
    twiddle7<-1>(v, (float)j * (1.0f/64.0f));
#pragma unroll
    for (int q = 0; q < 8; ++q) S[72*g + 9*q + j] = v[q];    // f2(64g+8q+j)
    wsync();
#pragma unroll
    for (int k = 0; k < 8; ++k) v[k] = S[9*l + k];           // f2(8l+k)
    bfly8<-1>(v);
}

// Inverse (unscaled, x512): input v[q] = value at position 8l+q, output
// v[k] = natural-order sample at h = l+64k. Exact mirror of fft512_fwd.
__device__ __forceinline__ void fft512_inv(float2 v[8], float2* S, int l) {
    const int g = l >> 3, j = l & 7;
    bfly8<1>(v);
#pragma unroll
    for (int k = 0; k < 8; ++k) S[9*l + k] = v[k];
    wsync();
#pragma unroll
    for (int q = 0; q < 8; ++q) v[q] = S[72*g + 9*q + j];
    twiddle7<1>(v, (float)j * (1.0f/64.0f));
    bfly8<1>(v);
#pragma unroll
    for (int k = 0; k < 8; ++k) S[66*g + j + 8*k] = v[k];
    wsync();
#pragma unroll
    for (int q = 0; q < 8; ++q) v[q] = S[66*q + l];
    twiddle7<1>(v, (float)l * (1.0f/512.0f));
    bfly8<1>(v);
}

__device__ __forceinline__ int drev(int x) {   // reverse 3 octal digits of 9-bit x
    return ((x & 7) << 6) | (x & 56) | (x >> 6);
}

// THIS ROUND: ws intermediate is FP16 complex (__half2) -- halves all four
// intermediate streams (768 -> ~514 MB total HBM traffic) and shrinks ws to
// 64 MB (L3-resident). The full 1/512^2 normalization is folded into Hp so
// pass2's fp16 output sits at |v| ~ 0.04 (no overflow; pass3 needs no scale).
// fp16 quantization adds ~5e-4 to the output vs the current 0.0156 absmax.

// Fused prologue + pass 1.
// Blocks 0..511: Hp[pw*512 + ph] = Hh[drev(ph)][drev(pw)] / 512^2, Hh =
// Hermitian part of the filter (for real x, Re(ifft2(fft2(x)*H)) ==
// ifft2(fft2(x)*Hh), a real linear map, so two planes pack as re/im of one
// complex plane).
// Blocks 512..8703: forward FFT along W, one row per wave, fp16 store.
__global__ __launch_bounds__(256) void pass1_rows(const float* __restrict__ x,
                                                  __half2* __restrict__ ws,
                                                  const float* __restrict__ Hr,
                                                  const float* __restrict__ Hi,
                                                  float2* __restrict__ Hp) {
    if (blockIdx.x < 512) {            // permH half
        const int pw = blockIdx.x;
        const int kw = drev(pw);
        const int nw = (512 - kw) & 511;
        const float s = 0.5f / (512.0f * 512.0f);
        for (int ph = threadIdx.x; ph < 512; ph += 256) {
            const int kh = drev(ph);
            const int nh = (512 - kh) & 511;
            const float hr = s * (Hr[(kh << 9) + kw] + Hr[(nh << 9) + nw]);
            const float hi = s * (Hi[(kh << 9) + kw] - Hi[(nh << 9) + nw]);
            Hp[(pw << 9) + ph] = make_float2(hr, hi);
        }
        return;
    }
    __shared__ float2 smem[4 * 577];
    const int t = threadIdx.x;
    const int l = t & 63, w = t >> 6;
    float2* S = smem + w * 577;
    const size_t row = (size_t)(blockIdx.x - 512) * 4 + w;  // 0..32767
    const size_t img = row >> 9;                     // packed plane 0..63
    const size_t h   = row & 511;
    const float* src1 = x + ((img * 2) << 18) + (h << 9);
    const float* src2 = src1 + (1 << 18);
    float2 v[8];
#pragma unroll
    for (int k = 0; k < 8; ++k) v[k] = make_float2(src1[l + 64*k], src2[l + 64*k]);
    fft512_fwd(v, S, l);
    __half2 ob[8];
#pragma unroll
    for (int q = 0; q < 8; ++q) ob[q] = __float22half2_rn(v[q]);
    float4* dst = (float4*)(ws + row * 512 + 8*l);   // 32B contiguous per lane
    dst[0] = *(float4*)&ob[0];
    dst[1] = *(float4*)&ob[4];
}

// Pass 2: 8 adjacent columns per block (512 thr = 8 waves), one column per
// wave. Coop line-complete fp16 staging (16B = 4 complex per lane); LDS is
// fp32; FFT scratch aliases the staging buffer.
__global__ __launch_bounds__(512) void pass2_cols(__half2* __restrict__ ws,
                                                  const float2* __restrict__ Hp) {
    __shared__ float2 smem[4616];      // staging 9*511+8 <= 4607; 8 scratches of 577
    const int t = threadIdx.x;
    const int l = t & 63, w = t >> 6;  // wave id == column-in-tile
    const int img = blockIdx.x >> 6;   // 0..63 packed planes
    const int w0 = (blockIdx.x & 63) * 8;
    __half2* base = ws + ((size_t)img << 18) + w0;

    {   // stage-in: 16B per lane = 4 fp16 complex (half the 8-col line each)
        const int c = t & 1, u = t >> 1;       // c: chunk, u: row 0..255
#pragma unroll
        for (int k = 0; k < 2; ++k) {
            int h = u + 256*k;
            float4 p = *(const float4*)(base + (size_t)h * 512 + 4*c);
            const __half2* pp = (const __half2*)&p;
#pragma unroll
            for (int i = 0; i < 4; ++i)
                smem[9*h + 4*c + i] = __half22float2(pp[i]);
        }
    }
    __syncthreads();
    float2 v[8];
#pragma unroll
    for (int k = 0; k < 8; ++k) v[k] = smem[9*(l + 64*k) + w];
    __syncthreads();                   // staging dead; scratch may alias it
    float2* S = smem + w * 577;
    fft512_fwd(v, S, l);
    {   // filter: kh = drev(8l+q), kw = drev(w0+w) -- pre-baked (incl. 1/512^2)
        const float4* hp = (const float4*)(Hp + (((size_t)(w0 + w)) << 9) + 8*l);
#pragma unroll
        for (int q = 0; q < 4; ++q) {
            float4 h2 = hp[q];
            v[2*q]   = cmul(v[2*q],   make_float2(h2.x, h2.y));
            v[2*q+1] = cmul(v[2*q+1], make_float2(h2.z, h2.w));
        }
    }
    fft512_inv(v, S, l);
    __syncthreads();                   // all waves done with scratch
#pragma unroll
    for (int k = 0; k < 8; ++k) smem[9*(l + 64*k) + w] = v[k];
    __syncthreads();
    {   // stage-out, 16B per lane, fp16
        const int c = t & 1, u = t >> 1;
#pragma unroll
        for (int k = 0; k < 2; ++k) {
            int h = u + 256*k;
            __half2 ob[4];
#pragma unroll
            for (int i = 0; i < 4; ++i)
                ob[i] = __float22half2_rn(smem[9*h + 4*c + i]);
            *(float4*)(base + (size_t)h * 512 + 4*c) = *(float4*)&ob[0];
        }
    }
}

// Pass 3: inverse FFT along W; unpack Re -> plane 2m, Im -> plane 2m+1.
// Normalization already folded into Hp; no scale here.
__global__ __launch_bounds__(256) void pass3_rows(const __half2* __restrict__ ws,
                                                  float* __restrict__ out) {
    __shared__ float2 smem[4 * 577];
    const int t = threadIdx.x;
    const int l = t & 63, w = t >> 6;
    float2* S = smem + w * 577;
    const size_t row = (size_t)blockIdx.x * 4 + w;   // 0..32767
    const size_t img = row >> 9;                     // 0..63
    const size_t h   = row & 511;
    const float4* src = (const float4*)(ws + row * 512 + 8*l);
    float4 a = src[0], b = src[1];
    float2 v[8];
    {
        const __half2* pa = (const __half2*)&a;
        const __half2* pb = (const __half2*)&b;
#pragma unroll
        for (int k = 0; k < 4; ++k) v[k]     = __half22float2(pa[k]);
#pragma unroll
        for (int k = 0; k < 4; ++k) v[4 + k] = __half22float2(pb[k]);
    }
    fft512_inv(v, S, l);
    float* dst1 = out + ((img * 2) << 18) + (h << 9);
    float* dst2 = dst1 + (1 << 18);
#pragma unroll
    for (int k = 0; k < 8; ++k) {
        dst1[l + 64*k] = v[k].x;
        dst2[l + 64*k] = v[k].y;
    }
}

extern "C" void kernel_launch(void* const* d_in, const int* in_sizes, int n_in,
                              void* d_out, int out_size, void* d_ws, size_t ws_size,
                              hipStream_t stream) {
    const float* x  = (const float*)d_in[0];   // [8,16,512,512]
    const float* Hr = (const float*)d_in[1];   // [512,512]
    const float* Hi = (const float*)d_in[2];   // [512,512]
    float* out = (float*)d_out;
    __half2* ws = (__half2*)d_ws;              // 64 MiB fp16 workspace (64 packed planes)
    float2* Hp = (float2*)((char*)d_ws + ((size_t)64 << 20));  // 2 MiB filter after ws

    pass1_rows<<<8704, 256, 0, stream>>>(x, ws, Hr, Hi, Hp);  // permH fused in
    pass2_cols<<<4096, 512, 0, stream>>>(ws, Hp);
    pass3_rows<<<8192, 256, 0, stream>>>(ws, out);
}

// Round 10
// 307.387 us; speedup vs baseline: 1.3080x; 1.0772x over previous
//
#include <hip/hip_runtime.h>
#include <hip/hip_fp16.h>

__device__ __forceinline__ float2 cmul(float2 a, float2 b) {
    return make_float2(a.x*b.x - a.y*b.y, a.x*b.y + a.y*b.x);
}
__device__ __forceinline__ float2 cadd(float2 a, float2 b){ return make_float2(a.x+b.x, a.y+b.y); }
__device__ __forceinline__ float2 csub(float2 a, float2 b){ return make_float2(a.x-b.x, a.y-b.y); }

// Wave-local LDS "barrier": all lane-exchange in the FFTs is within ONE wave
// (scratch regions are per-wave disjoint), so no s_barrier is needed.
__device__ __forceinline__ void wsync() {
    asm volatile("s_waitcnt lgkmcnt(0)" ::: "memory");
}

// multiply by (0, SGN): forward SGN=-1, inverse SGN=+1
template<int SGN> __device__ __forceinline__ float2 mul_i(float2 a) {
    return (SGN > 0) ? make_float2(-a.y, a.x) : make_float2(a.y, -a.x);
}
// W8^1 = (r, SGN*r), r = sqrt(0.5)
template<int SGN> __device__ __forceinline__ float2 mul_w81(float2 a) {
    const float r = 0.70710678118654752440f;
    return (SGN > 0) ? make_float2(r*(a.x - a.y), r*(a.x + a.y))
                     : make_float2(r*(a.x + a.y), r*(a.y - a.x));
}
// W8^3 = (-r, SGN*r)
template<int SGN> __device__ __forceinline__ float2 mul_w83(float2 a) {
    const float r = 0.70710678118654752440f;
    return (SGN > 0) ? make_float2(-r*(a.x + a.y), r*(a.x - a.y))
                     : make_float2(r*(a.y - a.x), -r*(a.x + a.y));
}

// 8-point DFT in registers, natural-order output: out[q] = sum_k in[k] W8^{SGN*qk}
template<int SGN>
__device__ __forceinline__ void bfly8(float2 v[8]) {
    float2 s0 = cadd(v[0], v[4]), d0 = csub(v[0], v[4]);
    float2 s1 = cadd(v[1], v[5]), d1 = csub(v[1], v[5]);
    float2 s2 = cadd(v[2], v[6]), d2 = csub(v[2], v[6]);
    float2 s3 = cadd(v[3], v[7]), d3 = csub(v[3], v[7]);
    d1 = mul_w81<SGN>(d1);
    d2 = mul_i<SGN>(d2);
    d3 = mul_w83<SGN>(d3);
    float2 p0 = cadd(s0, s2), q0 = csub(s0, s2);
    float2 p1 = cadd(s1, s3), q1 = mul_i<SGN>(csub(s1, s3));
    float2 P0 = cadd(d0, d2), Q0 = csub(d0, d2);
    float2 P1 = cadd(d1, d3), Q1 = mul_i<SGN>(csub(d1, d3));
    v[0] = cadd(p0, p1);
    v[4] = csub(p0, p1);
    v[2] = cadd(q0, q1);
    v[6] = csub(q0, q1);
    v[1] = cadd(P0, P1);
    v[5] = csub(P0, P1);
    v[3] = cadd(Q0, Q1);
    v[7] = csub(Q0, Q1);
}

// v[q] *= W^{SGN*q}, W = cis(2*pi*frac)
template<int SGN>
__device__ __forceinline__ void twiddle7(float2 v[8], float frac) {
    const float ang = (SGN > 0 ? 6.2831853071795864769f : -6.2831853071795864769f) * frac;
    float sn, cs; __sincosf(ang, &sn, &cs);
    const float2 w1 = make_float2(cs, sn);
    float2 w = w1;
    v[1] = cmul(v[1], w);
#pragma unroll
    for (int q = 2; q < 8; ++q) { w = cmul(w, w1); v[q] = cmul(v[q], w); }
}

// Forward 512-pt FFT, one wave, lane l (0..63), v preloaded with h = l+64k.
// Output: v[q] = spectrum value at position p = 8l+q (freq = octal-digit-rev(p)).
// S: per-wave scratch, >= 575 float2. Wave-local sync only -- no block barriers.
__device__ __forceinline__ void fft512_fwd(float2 v[8], float2* S, int l) {
    const int g = l >> 3, j = l & 7;
    bfly8<-1>(v);
    twiddle7<-1>(v, (float)l * (1.0f/512.0f));
#pragma unroll
    for (int q = 0; q < 8; ++q) S[66*q + l] = v[q];          // f1(64q+l)
    wsync();
#pragma unroll
    for (int k = 0; k < 8; ++k) v[k] = S[66*g + j + 8*k];    // f1(64g+j+8k)
    bfly8<-1>(v);
    twiddle7<-1>(v, (float)j * (1.0f/64.0f));
#pragma unroll
    for (int q = 0; q < 8; ++q) S[72*g + 9*q + j] = v[q];    // f2(64g+8q+j)
    wsync();
#pragma unroll
    for (int k = 0; k < 8; ++k) v[k] = S[9*l + k];           // f2(8l+k)
    bfly8<-1>(v);
}

// Inverse (unscaled, x512): input v[q] = value at position 8l+q, output
// v[k] = natural-order sample at h = l+64k. Exact mirror of fft512_fwd.
__device__ __forceinline__ void fft512_inv(float2 v[8], float2* S, int l) {
    const int g = l >> 3, j = l & 7;
    bfly8<1>(v);
#pragma unroll
    for (int k = 0; k < 8; ++k) S[9*l + k] = v[k];
    wsync();
#pragma unroll
    for (int q = 0; q < 8; ++q) v[q] = S[72*g + 9*q + j];
    twiddle7<1>(v, (float)j * (1.0f/64.0f));
    bfly8<1>(v);
#pragma unroll
    for (int k = 0; k < 8; ++k) S[66*g + j + 8*k] = v[k];
    wsync();
#pragma unroll
    for (int q = 0; q < 8; ++q) v[q] = S[66*q + l];
    twiddle7<1>(v, (float)l * (1.0f/512.0f));
    bfly8<1>(v);
}

__device__ __forceinline__ int drev(int x) {   // reverse 3 octal digits of 9-bit x
    return ((x & 7) << 6) | (x & 56) | (x >> 6);
}

// ws intermediate is FP16 complex (__half2): halves all four intermediate
// streams. Full 1/512^2 normalization folded into Hp so pass2's fp16 output
// sits at |v| ~ 0.04 and pass3 needs no scale.

// Fused prologue + pass 1.
// Blocks 0..511: Hp[pw*512 + ph] = Hh[drev(ph)][drev(pw)] / 512^2, Hh =
// Hermitian part of the filter (for real x, Re(ifft2(fft2(x)*H)) ==
// ifft2(fft2(x)*Hh), a real linear map, so two planes pack as re/im of one
// complex plane).
// Blocks 512..8703: forward FFT along W, one row per wave, fp16 store.
__global__ __launch_bounds__(256) void pass1_rows(const float* __restrict__ x,
                                                  __half2* __restrict__ ws,
                                                  const float* __restrict__ Hr,
                                                  const float* __restrict__ Hi,
                                                  float2* __restrict__ Hp) {
    if (blockIdx.x < 512) {            // permH half
        const int pw = blockIdx.x;
        const int kw = drev(pw);
        const int nw = (512 - kw) & 511;
        const float s = 0.5f / (512.0f * 512.0f);
        for (int ph = threadIdx.x; ph < 512; ph += 256) {
            const int kh = drev(ph);
            const int nh = (512 - kh) & 511;
            const float hr = s * (Hr[(kh << 9) + kw] + Hr[(nh << 9) + nw]);
            const float hi = s * (Hi[(kh << 9) + kw] - Hi[(nh << 9) + nw]);
            Hp[(pw << 9) + ph] = make_float2(hr, hi);
        }
        return;
    }
    __shared__ float2 smem[4 * 577];
    const int t = threadIdx.x;
    const int l = t & 63, w = t >> 6;
    float2* S = smem + w * 577;
    const size_t row = (size_t)(blockIdx.x - 512) * 4 + w;  // 0..32767
    const size_t img = row >> 9;                     // packed plane 0..63
    const size_t h   = row & 511;
    const float* src1 = x + ((img * 2) << 18) + (h << 9);
    const float* src2 = src1 + (1 << 18);
    float2 v[8];
#pragma unroll
    for (int k = 0; k < 8; ++k) v[k] = make_float2(src1[l + 64*k], src2[l + 64*k]);
    fft512_fwd(v, S, l);
    __half2 ob[8];
#pragma unroll
    for (int q = 0; q < 8; ++q) ob[q] = __float22half2_rn(v[q]);
    float4* dst = (float4*)(ws + row * 512 + 8*l);   // 32B contiguous per lane
    dst[0] = *(float4*)&ob[0];
    dst[1] = *(float4*)&ob[4];
}

// Pass 2 (THIS ROUND: 16-column tiles): with fp16 ws, an 8-column tile has a
// 32 B/row footprint -> 2x HBM read amplification at the 64 B fetch sector
// (measured: FETCH 134.9 MB on a 64 MB ws). 16 columns restores a full,
// aligned 64 B/row footprint. 512 thr = 8 waves; each wave runs TWO column
// FFTs back-to-back (per-wave scratch reused serially, wave-local).
// LDS staging is fp16 half2 with row stride 17 (coprime to 32 banks ->
// fragment reads conflict-free); staging (34.8 KB) aliases scratch (36.9 KB).
__global__ __launch_bounds__(512) void pass2_cols(__half2* __restrict__ ws,
                                                  const float2* __restrict__ Hp) {
    __shared__ float2 smem[4616];      // 8 scratches of 577 float2 = 36928 B
    __half2* sh = (__half2*)smem;      // staging view: [512 rows][stride 17]
    const int t = threadIdx.x;
    const int l = t & 63, w = t >> 6;  // wave id; wave handles cols 2w, 2w+1
    const int img = blockIdx.x >> 5;   // 0..63 packed planes
    const int w0 = (blockIdx.x & 31) * 16;   // 32 tiles of 16 columns
    __half2* base = ws + ((size_t)img << 18) + w0;

    {   // stage-in: 16B/lane = 4 half2; 4 chunks cover 64 B/row
        const int c = t & 3, u = t >> 2;     // c: 16B chunk, u: row 0..127
#pragma unroll
        for (int k = 0; k < 4; ++k) {
            int h = u + 128*k;
            float4 p = *(const float4*)(base + (size_t)h * 512 + 4*c);
            const __half2* pp = (const __half2*)&p;
#pragma unroll
            for (int i = 0; i < 4; ++i) sh[17*h + 4*c + i] = pp[i];
        }
    }
    __syncthreads();
    float2 va[8], vb[8];
    const int c0 = 2*w, c1 = 2*w + 1;
#pragma unroll
    for (int k = 0; k < 8; ++k) {
        va[k] = __half22float2(sh[17*(l + 64*k) + c0]);
        vb[k] = __half22float2(sh[17*(l + 64*k) + c1]);
    }
    __syncthreads();                   // staging dead; scratch may alias it
    float2* S = smem + w * 577;
    fft512_fwd(va, S, l);
    {   // filter col w0+c0: kh = drev(8l+q) pre-baked into Hp (incl. 1/512^2)
        const float4* hp = (const float4*)(Hp + (((size_t)(w0 + c0)) << 9) + 8*l);
#pragma unroll
        for (int q = 0; q < 4; ++q) {
            float4 h2 = hp[q];
            va[2*q]   = cmul(va[2*q],   make_float2(h2.x, h2.y));
            va[2*q+1] = cmul(va[2*q+1], make_float2(h2.z, h2.w));
        }
    }
    fft512_inv(va, S, l);
    fft512_fwd(vb, S, l);
    {   // filter col w0+c1
        const float4* hp = (const float4*)(Hp + (((size_t)(w0 + c1)) << 9) + 8*l);
#pragma unroll
        for (int q = 0; q < 4; ++q) {
            float4 h2 = hp[q];
            vb[2*q]   = cmul(vb[2*q],   make_float2(h2.x, h2.y));
            vb[2*q+1] = cmul(vb[2*q+1], make_float2(h2.z, h2.w));
        }
    }
    fft512_inv(vb, S, l);
    __syncthreads();                   // all waves done with scratch
#pragma unroll
    for (int k = 0; k < 8; ++k) {
        sh[17*(l + 64*k) + c0] = __float22half2_rn(va[k]);
        sh[17*(l + 64*k) + c1] = __float22half2_rn(vb[k]);
    }
    __syncthreads();
    {   // stage-out, mirror of stage-in
        const int c = t & 3, u = t >> 2;
#pragma unroll
        for (int k = 0; k < 4; ++k) {
            int h = u + 128*k;
            __half2 ob[4];
#pragma unroll
            for (int i = 0; i < 4; ++i) ob[i] = sh[17*h + 4*c + i];
            *(float4*)(base + (size_t)h * 512 + 4*c) = *(float4*)&ob[0];
        }
    }
}

// Pass 3: inverse FFT along W; unpack Re -> plane 2m, Im -> plane 2m+1.
// Normalization already folded into Hp; no scale here.
__global__ __launch_bounds__(256) void pass3_rows(const __half2* __restrict__ ws,
                                                  float* __restrict__ out) {
    __shared__ float2 smem[4 * 577];
    const int t = threadIdx.x;
    const int l = t & 63, w = t >> 6;
    float2* S = smem + w * 577;
    const size_t row = (size_t)blockIdx.x * 4 + w;   // 0..32767
    const size_t img = row >> 9;                     // 0..63
    const size_t h   = row & 511;
    const float4* src = (const float4*)(ws + row * 512 + 8*l);
    float4 a = src[0], b = src[1];
    float2 v[8];
    {
        const __half2* pa = (const __half2*)&a;
        const __half2* pb = (const __half2*)&b;
#pragma unroll
        for (int k = 0; k < 4; ++k) v[k]     = __half22float2(pa[k]);
#pragma unroll
        for (int k = 0; k < 4; ++k) v[4 + k] = __half22float2(pb[k]);
    }
    fft512_inv(v, S, l);
    float* dst1 = out + ((img * 2) << 18) + (h << 9);
    float* dst2 = dst1 + (1 << 18);
#pragma unroll
    for (int k = 0; k < 8; ++k) {
        dst1[l + 64*k] = v[k].x;
        dst2[l + 64*k] = v[k].y;
    }
}

extern "C" void kernel_launch(void* const* d_in, const int* in_sizes, int n_in,
                              void* d_out, int out_size, void* d_ws, size_t ws_size,
                              hipStream_t stream) {
    const float* x  = (const float*)d_in[0];   // [8,16,512,512]
    const float* Hr = (const float*)d_in[1];   // [512,512]
    const float* Hi = (const float*)d_in[2];   // [512,512]
    float* out = (float*)d_out;
    __half2* ws = (__half2*)d_ws;              // 64 MiB fp16 workspace (64 packed planes)
    float2* Hp = (float2*)((char*)d_ws + ((size_t)64 << 20));  // 2 MiB filter after ws

    pass1_rows<<<8704, 256, 0, stream>>>(x, ws, Hr, Hi, Hp);  // permH fused in
    pass2_cols<<<2048, 512, 0, stream>>>(ws, Hp);
    pass3_rows<<<8192, 256, 0, stream>>>(ws, out);
}